// Round 15
// baseline (85.656 us; speedup 1.0000x reference)
//
#include <hip/hip_runtime.h>
#include <math.h>

#define NROWS 4096
#define DIM   512
#define BT    256           // block tile edge
#define BK    32            // K-tile
#define NKT   (DIM / BK)    // 16
#define NTC   (NROWS / BT)  // 16
#define NBLK  (NTC * NTC)   // 256 blocks, 1 per CU

typedef __attribute__((ext_vector_type(4))) float f32x4;
typedef __attribute__((ext_vector_type(8))) short bf16x8;

// ws layout (bytes):
// [0,      16384)    float mag[4096]
// [16384,  32768)    float row_neg[4096]
// [32768,  32784)    double loss | uint pair_cnt | uint done
// [32800,  163872)   ushort part_t[4096][16]  (bf16 negsum partials)
// [163872, 4358176)  unsigned short Xb[4096*512]
// [4358176, ...)     pairs: uint2 {(i<<16)|j, float_bits(dist)}
#define PART_OFF 32800
#define XB_OFF   (PART_OFF + NROWS * NTC * 2)      // 163872
#define PAIR_OFF (XB_OFF + NROWS * DIM * 2)        // 4358176

__device__ inline unsigned short f2bf(float f) {
    unsigned int u = __float_as_uint(f);
    unsigned int r = (u + 0x7fffu + ((u >> 16) & 1u)) >> 16;   // RTNE
    return (unsigned short)r;
}
__device__ inline float bf2f(unsigned short u) {
    return __uint_as_float((unsigned int)u << 16);
}

__global__ void prep_kernel(const float* __restrict__ X,
                            unsigned short* __restrict__ Xb,
                            float* __restrict__ mag,
                            unsigned int* __restrict__ ctrl) {
    if (blockIdx.x == 0 && threadIdx.x < 4) ctrl[threadIdx.x] = 0u;
    int row  = blockIdx.x * 4 + (threadIdx.x >> 6);
    int lane = threadIdx.x & 63;
    const float4* p = reinterpret_cast<const float4*>(X + (size_t)row * DIM);
    short4* o = reinterpret_cast<short4*>(Xb + (size_t)row * DIM);
    float s = 0.f;
#pragma unroll
    for (int q = lane; q < DIM / 4; q += 64) {
        float4 v = p[q];
        s += v.x * v.x + v.y * v.y + v.z * v.z + v.w * v.w;
        short4 b;
        b.x = (short)f2bf(v.x); b.y = (short)f2bf(v.y);
        b.z = (short)f2bf(v.z); b.w = (short)f2bf(v.w);
        o[q] = b;
    }
#pragma unroll
    for (int off = 32; off; off >>= 1) s += __shfl_down(s, off);
    if (lane == 0) mag[row] = s;
}

// 256x256 full-matrix tile, 8 waves (2Mx4N), BK=32, 3-buffer depth-2
// counted-vmcnt pipeline (loads never drained in the loop).
__global__ __launch_bounds__(512, 2) void sim_mfma(
        const unsigned short* __restrict__ Xb, const int* __restrict__ tgt,
        const float* __restrict__ mag, unsigned short* __restrict__ part,
        unsigned int* __restrict__ pair_cnt, uint2* __restrict__ pairs,
        unsigned int cap) {
    __shared__ unsigned short As[3][BT * BK];   // 3 x 16 KB
    __shared__ unsigned short Bs[3][BT * BK];   // 3 x 16 KB  (96 KB total)

    const int tid  = threadIdx.x;
    const int lane = tid & 63;
    const int wid  = tid >> 6;        // 8 waves
    const int wm   = wid >> 2;        // 0..1  (128-row strip)
    const int wn   = wid & 3;         // 0..3  (64-col strip)
    const int l15  = lane & 15;
    const int lg   = lane >> 4;       // 0..3

    // XCD-rect mapping: XCD x = b&7 owns a 4x8 tile rectangle (bijective)
    int b  = blockIdx.x;
    int x  = b & 7, w8 = b >> 3;
    int bi = (x >> 1) * 4 + (w8 >> 3);
    int bj = (x & 1) * 8 + (w8 & 7);
    const int rowBase = bi * BT;
    const int colBase = bj * BT;

    // ---- staging constants: thread stages chunk ch of row rL (per half) ----
    // swizzle: LDS[r][ch] = global[r][ch ^ swz(r)], swz(r)=(r+(r>>2))&3
    const int rL  = tid >> 2;
    const int ch  = tid & 3;
    const int gch = ch ^ ((rL + (rL >> 2)) & 3);
    const unsigned short* srcA0 = Xb + (size_t)(rowBase + rL) * DIM + gch * 8;
    const unsigned short* srcA1 = srcA0 + (size_t)128 * DIM;
    const unsigned short* srcB0 = Xb + (size_t)(colBase + rL) * DIM + gch * 8;
    const unsigned short* srcB1 = srcB0 + (size_t)128 * DIM;
    const int dstOff = wid * 512;     // wave-uniform elem offset (+ lane*8 by HW)

#define STAGE(bufi, kt2)                                                      \
    {                                                                         \
        const int k0 = (kt2) * BK;                                            \
        __builtin_amdgcn_global_load_lds(                                     \
            (const __attribute__((address_space(1))) void*)(srcA0 + k0),      \
            (__attribute__((address_space(3))) void*)(&As[bufi][dstOff]),     \
            16, 0, 0);                                                        \
        __builtin_amdgcn_global_load_lds(                                     \
            (const __attribute__((address_space(1))) void*)(srcA1 + k0),      \
            (__attribute__((address_space(3))) void*)(&As[bufi][4096 + dstOff]),\
            16, 0, 0);                                                        \
        __builtin_amdgcn_global_load_lds(                                     \
            (const __attribute__((address_space(1))) void*)(srcB0 + k0),      \
            (__attribute__((address_space(3))) void*)(&Bs[bufi][dstOff]),     \
            16, 0, 0);                                                        \
        __builtin_amdgcn_global_load_lds(                                     \
            (const __attribute__((address_space(1))) void*)(srcB1 + k0),      \
            (__attribute__((address_space(3))) void*)(&Bs[bufi][4096 + dstOff]),\
            16, 0, 0);                                                        \
    }

    f32x4 acc[8][4];
#pragma unroll
    for (int m = 0; m < 8; m++)
#pragma unroll
        for (int n = 0; n < 4; n++) acc[m][n] = (f32x4){0.f, 0.f, 0.f, 0.f};

    // fragment LDS element offsets (constant per thread, + buf base per iter)
    int aOff[8], bOff[4];
#pragma unroll
    for (int m = 0; m < 8; m++) {
        int ra = wm * 128 + m * 16 + l15;
        aOff[m] = ra * BK + ((lg ^ ((ra + (ra >> 2)) & 3)) * 8);
    }
#pragma unroll
    for (int n = 0; n < 4; n++) {
        int rb = wn * 64 + n * 16 + l15;
        bOff[n] = rb * BK + ((lg ^ ((rb + (rb >> 2)) & 3)) * 8);
    }

    // prologue: 2 K-tiles in flight (8 loads/wave)
    STAGE(0, 0)
    STAGE(1, 1)

    int buf = 0;
#pragma unroll 1
    for (int kt = 0; kt < NKT; kt++) {
        // boundary: force kt's 4 loads (2 groups old) complete; keep kt+1's
        // 4 in flight. Never drain to 0 except the final peel.
        if (kt < NKT - 1) asm volatile("s_waitcnt vmcnt(4)" ::: "memory");
        else              asm volatile("s_waitcnt vmcnt(0)" ::: "memory");
        __builtin_amdgcn_s_barrier();
        __builtin_amdgcn_sched_barrier(0);

        if (kt + 2 < NKT) {
            int bufS = (buf >= 1) ? buf - 1 : 2;   // (buf+2)%3
            STAGE(bufS, kt + 2)
        }

        const unsigned short* Ab = &As[buf][0];
        const unsigned short* Bb = &Bs[buf][0];
        bf16x8 bf[4], af[8];
#pragma unroll
        for (int n = 0; n < 4; n++)
            bf[n] = *reinterpret_cast<const bf16x8*>(Bb + bOff[n]);
#pragma unroll
        for (int m = 0; m < 8; m++)
            af[m] = *reinterpret_cast<const bf16x8*>(Ab + aOff[m]);
#pragma unroll
        for (int m = 0; m < 8; m++)
#pragma unroll
            for (int n = 0; n < 4; n++)
                acc[m][n] = __builtin_amdgcn_mfma_f32_16x16x32_bf16(
                    af[m], bf[n], acc[m][n], 0, 0, 0);

        buf = (buf == 2) ? 0 : buf + 1;
    }
#undef STAGE

    // ---- fused epilogue (full matrix: row-side only, no col-side) ----
    __syncthreads();                       // K-loop LDS dead; overlay buffers
    float* rowpart = (float*)&As[0][0];    // [4][256] floats = 4 KB
    unsigned int* scan = (unsigned int*)&Bs[0][0];

    int   gcol[4], tgj[4];
    float mj[4];
#pragma unroll
    for (int n = 0; n < 4; n++) {
        gcol[n] = colBase + wn * 64 + n * 16 + l15;
        tgj[n]  = tgt[gcol[n]];
        mj[n]   = mag[gcol[n]];
    }

    int mycnt = 0;
#pragma unroll
    for (int m = 0; m < 8; m++) {
        int   grow_[4], tgi_[4];
        float mi_[4];
#pragma unroll
        for (int q = 0; q < 4; q++) {
            grow_[q] = rowBase + wm * 128 + m * 16 + lg * 4 + q;
            tgi_[q]  = tgt[grow_[q]];
            mi_[q]   = mag[grow_[q]];
        }
        float negq[4] = {0.f, 0.f, 0.f, 0.f};
#pragma unroll
        for (int n = 0; n < 4; n++)
#pragma unroll
            for (int q = 0; q < 4; q++) {
                float d2   = mi_[q] + mj[n] - 2.f * acc[m][n][q];
                float dist = d2 > 0.f ? sqrtf(d2) : 0.f;
                acc[m][n][q] = dist;
                if (tgi_[q] != tgj[n]) {
                    if (dist != 0.f) negq[q] += __expf(1.0f - dist);
                } else if (grow_[q] < gcol[n]) {
                    mycnt++;
                }
            }
#pragma unroll
        for (int q = 0; q < 4; q++) {
            float v = negq[q];
            v += __shfl_xor(v, 1); v += __shfl_xor(v, 2);
            v += __shfl_xor(v, 4); v += __shfl_xor(v, 8);
            if (l15 == 0) rowpart[wn * 256 + wm * 128 + m * 16 + lg * 4 + q] = v;
        }
    }

    // pair-count scan: wave-level inclusive prefix, then 8-wave block scan
    unsigned int pc = (unsigned int)mycnt;
    unsigned int incl = pc;
#pragma unroll
    for (int d = 1; d < 64; d <<= 1) {
        unsigned int tshf = __shfl_up(incl, d);
        if (lane >= d) incl += tshf;
    }
    if (lane == 63) scan[wid] = incl;
    __syncthreads();

    // collision-free partial store: part_t[row][bj], unique writer per slot
    if (tid < BT) {
        float s = rowpart[tid] + rowpart[256 + tid] + rowpart[512 + tid] +
                  rowpart[768 + tid];
        part[(size_t)(rowBase + tid) * NTC + bj] = f2bf(s);
    }

    unsigned int woff = 0;
#pragma unroll
    for (int w = 0; w < 8; w++)
        if (w < wid) woff += scan[w];
    unsigned int btot = 0;
#pragma unroll
    for (int w = 0; w < 8; w++) btot += scan[w];
    if (tid == 0) scan[8] = btot ? atomicAdd(pair_cnt, btot) : 0u;
    __syncthreads();
    unsigned int mybase = scan[8] + woff + (incl - pc);

    // pass B: write pairs (dist already in acc)
    if (pc) {
        unsigned int idx = mybase;
#pragma unroll
        for (int m = 0; m < 8; m++) {
            int grow_[4], tgi_[4];
#pragma unroll
            for (int q = 0; q < 4; q++) {
                grow_[q] = rowBase + wm * 128 + m * 16 + lg * 4 + q;
                tgi_[q]  = tgt[grow_[q]];
            }
#pragma unroll
            for (int n = 0; n < 4; n++)
#pragma unroll
                for (int q = 0; q < 4; q++) {
                    if (tgi_[q] == tgj[n] && grow_[q] < gcol[n]) {
                        if (idx < cap) {
                            uint2 e;
                            e.x = ((unsigned int)grow_[q] << 16) | (unsigned int)gcol[n];
                            e.y = (unsigned int)__float_as_int(acc[m][n][q]);
                            pairs[idx] = e;
                        }
                        idx++;
                    }
                }
        }
    }
}

// row_neg[r] = sum of 16 bf16 partials (32B stripe per row)
__global__ void reduce_kernel(const unsigned short* __restrict__ part,
                              float* __restrict__ row_neg) {
    int r = blockIdx.x * 256 + threadIdx.x;
    const bf16x8* p = reinterpret_cast<const bf16x8*>(part + (size_t)r * NTC);
    float s = 0.f;
#pragma unroll
    for (int k = 0; k < 2; k++) {
        bf16x8 a = p[k];
#pragma unroll
        for (int u = 0; u < 8; u++) s += bf2f((unsigned short)a[u]);
    }
    row_neg[r] = s;
}

// pair loss sum + fused finalize
__global__ void pair_kernel(const uint2* __restrict__ pairs,
                            const unsigned int* __restrict__ pair_cnt,
                            const float* __restrict__ row_neg,
                            unsigned int cap, double* __restrict__ loss,
                            unsigned int* __restrict__ done,
                            float* __restrict__ out) {
    __shared__ double red[256];
    unsigned int n = *pair_cnt;
    if (n > cap) n = cap;
    double local = 0.0;
    for (unsigned int p = blockIdx.x * blockDim.x + threadIdx.x; p < n;
         p += gridDim.x * blockDim.x) {
        uint2 e = pairs[p];
        int i = (int)(e.x >> 16), j = (int)(e.x & 0xffffu);
        float d = __int_as_float((int)e.y);
        float J = logf(row_neg[i] + row_neg[j]) + d;
        if (J > 0.f) local += (double)J * (double)J;
    }
    red[threadIdx.x] = local;
    __syncthreads();
    for (int s = 128; s; s >>= 1) {
        if (threadIdx.x < (unsigned)s) red[threadIdx.x] += red[threadIdx.x + s];
        __syncthreads();
    }
    if (threadIdx.x == 0) {
        atomicAdd(loss, red[0]);
        __threadfence();
        unsigned int tk = atomicAdd(done, 1u);
        if (tk == gridDim.x - 1) {
            double l = atomicAdd(loss, 0.0);   // coherent read after all adds
            out[0] = (float)(l / (2.0 * (double)(*pair_cnt)));
        }
    }
}

extern "C" void kernel_launch(void* const* d_in, const int* in_sizes, int n_in,
                              void* d_out, int out_size, void* d_ws, size_t ws_size,
                              hipStream_t stream) {
    const float* X = (const float*)d_in[0];
    const int* tgt = (const int*)d_in[1];
    float* out = (float*)d_out;

    char* ws = (char*)d_ws;
    float* mag             = (float*)(ws + 0);
    float* row_neg         = (float*)(ws + 16384);
    double* loss           = (double*)(ws + 32768);
    unsigned int* pair_cnt = (unsigned int*)(ws + 32776);
    unsigned int* done     = (unsigned int*)(ws + 32780);
    unsigned int* ctrl     = (unsigned int*)(ws + 32768);
    unsigned short* part   = (unsigned short*)(ws + PART_OFF);
    unsigned short* Xb     = (unsigned short*)(ws + XB_OFF);
    uint2* pairs           = (uint2*)(ws + PAIR_OFF);
    unsigned int cap = 0;
    if (ws_size > PAIR_OFF + 8) cap = (unsigned int)((ws_size - PAIR_OFF) / 8);

    prep_kernel<<<NROWS / 4, 256, 0, stream>>>(X, Xb, mag, ctrl);

    sim_mfma<<<NBLK, 512, 0, stream>>>(Xb, tgt, mag, part, pair_cnt, pairs, cap);

    reduce_kernel<<<NROWS / 256, 256, 0, stream>>>(part, row_neg);

    pair_kernel<<<256, 256, 0, stream>>>(pairs, pair_cnt, row_neg, cap, loss,
                                         done, out);
}

// Round 16
// 68.205 us; speedup vs baseline: 1.2559x; 1.2559x over previous
//
#include <hip/hip_runtime.h>
#include <math.h>

#define NROWS 4096
#define DIM   512
#define BM    128
#define BKB   128               // K-tile in elements(=bytes, int8)
#define NKT   (DIM / BKB)       // 4
#define NTILE (NROWS / BM)      // 32
#define NBLK  (NTILE * (NTILE + 1) / 2)  // 528 (= 8 x 66)

typedef __attribute__((ext_vector_type(4))) float f32x4;
typedef __attribute__((ext_vector_type(4))) int   i32x4;
typedef __attribute__((ext_vector_type(8))) short bf16x8;

// ws layout (bytes):
// [0, 32)            ctrl: double loss | uint pair_cnt | uint done | uint absmax_bits | pad
// [64,    16448)     int   mag[4096]
// [16448, 32832)     float row_neg[4096]
// [32832, 294976)    ushort part_t[4096][32]  (bf16 negsum partials)
// [294976, 2392128)  int8 Xq[4096*512]  (2 MB)
// [2392128, ...)     pairs: uint2 {(i<<16)|j, float_bits(dist)}
#define CTRL_OFF 0
#define MAGI_OFF 64
#define RN_OFF   (MAGI_OFF + NROWS * 4)            // 16448
#define PART_OFF (RN_OFF + NROWS * 4)              // 32832
#define XQ_OFF   (PART_OFF + NROWS * NTILE * 2)    // 294976
#define PAIR_OFF (XQ_OFF + NROWS * DIM)            // 2392128

__device__ inline unsigned short f2bf(float f) {
    unsigned int u = __float_as_uint(f);
    unsigned int r = (u + 0x7fffu + ((u >> 16) & 1u)) >> 16;   // RTNE
    return (unsigned short)r;
}
__device__ inline float bf2f(unsigned short u) {
    return __uint_as_float((unsigned int)u << 16);
}

// pass 1: global abs-max (ctrl pre-zeroed by memset)
__global__ void absmax_kernel(const float* __restrict__ X,
                              unsigned int* __restrict__ absmax_u) {
    float m = 0.f;
    for (int i = blockIdx.x * blockDim.x + threadIdx.x; i < NROWS * DIM / 4;
         i += gridDim.x * blockDim.x) {
        float4 v = reinterpret_cast<const float4*>(X)[i];
        m = fmaxf(m, fmaxf(fmaxf(fabsf(v.x), fabsf(v.y)),
                           fmaxf(fabsf(v.z), fabsf(v.w))));
    }
#pragma unroll
    for (int o = 32; o; o >>= 1) m = fmaxf(m, __shfl_down(m, o));
    if ((threadIdx.x & 63) == 0)
        atomicMax(absmax_u, __float_as_uint(m));   // positive floats: uint order ok
}

// pass 2: quantize to int8 + exact int row sq-norms
__global__ void quant_kernel(const float* __restrict__ X,
                             signed char* __restrict__ Xq,
                             int* __restrict__ mag,
                             const unsigned int* __restrict__ absmax_u) {
    float absm = __uint_as_float(*absmax_u);
    float s = absm > 1e-20f ? 126.0f / absm : 1.0f;
    int row  = blockIdx.x * 4 + (threadIdx.x >> 6);
    int lane = threadIdx.x & 63;
    const float4* p = reinterpret_cast<const float4*>(X + (size_t)row * DIM);
    unsigned int* o = reinterpret_cast<unsigned int*>(Xq + (size_t)row * DIM);
    int acc = 0;
#pragma unroll
    for (int q = lane; q < DIM / 4; q += 64) {
        float4 v = p[q];
        int c0 = (int)rintf(v.x * s), c1 = (int)rintf(v.y * s);
        int c2 = (int)rintf(v.z * s), c3 = (int)rintf(v.w * s);
        c0 = max(-127, min(127, c0)); c1 = max(-127, min(127, c1));
        c2 = max(-127, min(127, c2)); c3 = max(-127, min(127, c3));
        acc += c0 * c0 + c1 * c1 + c2 * c2 + c3 * c3;
        o[q] = (unsigned int)(c0 & 255) | ((unsigned int)(c1 & 255) << 8) |
               ((unsigned int)(c2 & 255) << 16) | ((unsigned int)(c3 & 255) << 24);
    }
#pragma unroll
    for (int off = 32; off; off >>= 1) acc += __shfl_down(acc, off);
    if (lane == 0) mag[row] = acc;
}

// int8 MFMA GEMM, exact integer distances. 1:1 port of the R11 structure:
// 128x128 triangular tiles, rolled K-loop, 8x16B-chunk XOR swizzle.
__global__ __launch_bounds__(256, 3) void sim_mfma(
        const signed char* __restrict__ Xq, const int* __restrict__ tgt,
        const int* __restrict__ mag, const unsigned int* __restrict__ absmax_u,
        unsigned short* __restrict__ part,
        unsigned int* __restrict__ pair_cnt, uint2* __restrict__ pairs,
        unsigned int cap) {
    __shared__ signed char As[BM * BKB];   // 16 KB
    __shared__ signed char Bs[BM * BKB];   // 16 KB

    const int tid  = threadIdx.x;
    const int lane = tid & 63;
    const int wid  = tid >> 6;        // 4 waves: 2x2 of 64x64
    const int wr   = wid >> 1, wc = wid & 1;
    const int l15  = lane & 15;
    const int lg   = lane >> 4;       // 0..3

    const float inv_s = __uint_as_float(*absmax_u) * (1.0f / 126.0f);

    // XCD swizzle: 528 = 8 x 66, contiguous runs per XCD
    int b = blockIdx.x;
    int t = (b & 7) * 66 + (b >> 3);
    int bi = (int)((65.0f - sqrtf(4225.0f - 8.0f * (float)t)) * 0.5f);
    if (bi < 0) bi = 0;
    if (bi > NTILE - 1) bi = NTILE - 1;
    while ((65 * (bi + 1) - (bi + 1) * (bi + 1)) / 2 <= t) bi++;
    while ((65 * bi - bi * bi) / 2 > t) bi--;
    int bj = bi + (t - (65 * bi - bi * bi) / 2);
    const int rowBase = bi * BM;
    const int colBase = bj * BM;
    const bool offd = (bi != bj);

    i32x4 acc[4][4];
#pragma unroll
    for (int m = 0; m < 4; m++)
#pragma unroll
        for (int n = 0; n < 4; n++) acc[m][n] = (i32x4){0, 0, 0, 0};

    // ROLLED K-loop. Row = 128 B = 8 x 16B chunks; LDS slot (r, ch) holds
    // global chunk ch^(r&7) (read-side XOR, linear LDS dest - rule #21).
#pragma unroll 1
    for (int kt = 0; kt < NKT; kt++) {
        const int k0 = kt * BKB;
        __syncthreads();
#pragma unroll
        for (int c = 0; c < 4; c++) {
            int chunkBase = (c * 4 + wid) * 64;      // wave-uniform
            int idx = chunkBase + lane;              // 0..1023
            int r   = idx >> 3;
            int ch  = idx & 7;
            int gch = ch ^ (r & 7);
            const signed char* ga = Xq + (size_t)(rowBase + r) * DIM + k0 + gch * 16;
            __builtin_amdgcn_global_load_lds(
                (const __attribute__((address_space(1))) void*)ga,
                (__attribute__((address_space(3))) void*)(As + chunkBase * 16),
                16, 0, 0);
            const signed char* gb = Xq + (size_t)(colBase + r) * DIM + k0 + gch * 16;
            __builtin_amdgcn_global_load_lds(
                (const __attribute__((address_space(1))) void*)gb,
                (__attribute__((address_space(3))) void*)(Bs + chunkBase * 16),
                16, 0, 0);
        }
        __syncthreads();

#pragma unroll
        for (int ksub = 0; ksub < 2; ksub++) {
            i32x4 af[4], bf[4];
#pragma unroll
            for (int m = 0; m < 4; m++) {
                int ra = wr * 64 + m * 16 + l15;
                int cs = (ksub * 4 + lg) ^ (ra & 7);
                af[m] = *reinterpret_cast<const i32x4*>(&As[ra * BKB + cs * 16]);
            }
#pragma unroll
            for (int n = 0; n < 4; n++) {
                int rb = wc * 64 + n * 16 + l15;
                int cs = (ksub * 4 + lg) ^ (rb & 7);
                bf[n] = *reinterpret_cast<const i32x4*>(&Bs[rb * BKB + cs * 16]);
            }
#pragma unroll
            for (int m = 0; m < 4; m++)
#pragma unroll
                for (int n = 0; n < 4; n++)
                    acc[m][n] = __builtin_amdgcn_mfma_i32_16x16x64_i8(
                        af[m], bf[n], acc[m][n], 0, 0, 0);
        }
    }

    // ---- fused epilogue ----
    // C/D layout: col = lane&15, row = (lane>>4)*4 + reg (dtype-independent)
    int gcol[4], tgj[4], mj[4];
#pragma unroll
    for (int n = 0; n < 4; n++) {
        gcol[n] = colBase + wc * 64 + n * 16 + l15;
        tgj[n]  = tgt[gcol[n]];
        mj[n]   = mag[gcol[n]];
    }
    int grow[4][4], tgi[4][4], mi[4][4];
#pragma unroll
    for (int m = 0; m < 4; m++)
#pragma unroll
        for (int q = 0; q < 4; q++) {
            grow[m][q] = rowBase + wr * 64 + m * 16 + lg * 4 + q;
            tgi[m][q]  = tgt[grow[m][q]];
            mi[m][q]   = mag[grow[m][q]];
        }

    float negrow[4][4];
    float negcol[4] = {0.f, 0.f, 0.f, 0.f};
#pragma unroll
    for (int m = 0; m < 4; m++)
#pragma unroll
        for (int q = 0; q < 4; q++) negrow[m][q] = 0.f;

    // pass A: exact int d2 -> dist (overwrites acc with dist bits)
    int mycnt = 0;
#pragma unroll
    for (int m = 0; m < 4; m++)
#pragma unroll
        for (int n = 0; n < 4; n++)
#pragma unroll
            for (int q = 0; q < 4; q++) {
                int   d2   = mi[m][q] + mj[n] - 2 * acc[m][n][q];
                float dist = d2 > 0 ? sqrtf((float)d2) * inv_s : 0.f;
                acc[m][n][q] = __float_as_int(dist);
                if (tgi[m][q] != tgj[n]) {
                    if (d2 > 0) {
                        float e = __expf(1.0f - dist);
                        negrow[m][q] += e;
                        if (offd) negcol[n] += e;
                    }
                } else if (grow[m][q] < gcol[n]) {
                    mycnt++;
                }
            }

    __syncthreads();   // K-loop LDS dead; overlay epilogue buffers
    float* rowbuf = (float*)&As[0];            // [2][128] floats
    float* colbuf = (float*)&As[1024 * 2];     // [2][128] floats
    unsigned int* scan = (unsigned int*)&Bs[0];

#pragma unroll
    for (int m = 0; m < 4; m++)
#pragma unroll
        for (int q = 0; q < 4; q++) {
            float v = negrow[m][q];
            v += __shfl_xor(v, 1); v += __shfl_xor(v, 2);
            v += __shfl_xor(v, 4); v += __shfl_xor(v, 8);
            if (l15 == 0) rowbuf[wc * 128 + wr * 64 + m * 16 + lg * 4 + q] = v;
        }
#pragma unroll
    for (int n = 0; n < 4; n++) {
        float v = negcol[n];
        v += __shfl_xor(v, 16); v += __shfl_xor(v, 32);
        if (lg == 0) colbuf[wr * 128 + wc * 64 + n * 16 + l15] = v;
    }

    unsigned int pc = (unsigned int)mycnt;
    unsigned int incl = pc;
#pragma unroll
    for (int d = 1; d < 64; d <<= 1) {
        unsigned int tshf = __shfl_up(incl, d);
        if (lane >= d) incl += tshf;
    }
    if (lane == 63) scan[wid] = incl;
    __syncthreads();

    if (tid < BM) {
        float rv = rowbuf[tid] + rowbuf[128 + tid];
        part[(size_t)(rowBase + tid) * NTILE + bj] = f2bf(rv);
        if (offd) {
            float cv = colbuf[tid] + colbuf[128 + tid];
            part[(size_t)(colBase + tid) * NTILE + bi] = f2bf(cv);
        }
    }

    unsigned int woff = 0;
#pragma unroll
    for (int w = 0; w < 4; w++)
        if (w < wid) woff += scan[w];
    unsigned int btot = scan[0] + scan[1] + scan[2] + scan[3];
    if (tid == 0) scan[4] = btot ? atomicAdd(pair_cnt, btot) : 0u;
    __syncthreads();
    unsigned int mybase = scan[4] + woff + (incl - pc);

    if (pc) {
        unsigned int idx = mybase;
#pragma unroll
        for (int m = 0; m < 4; m++)
#pragma unroll
            for (int n = 0; n < 4; n++)
#pragma unroll
                for (int q = 0; q < 4; q++) {
                    if (tgi[m][q] == tgj[n] && grow[m][q] < gcol[n]) {
                        if (idx < cap) {
                            uint2 e;
                            e.x = ((unsigned int)grow[m][q] << 16) | (unsigned int)gcol[n];
                            e.y = (unsigned int)acc[m][n][q];   // dist bits
                            pairs[idx] = e;
                        }
                        idx++;
                    }
                }
    }
}

// row_neg[r] = sum of 32 bf16 partials (contiguous 64B stripe per row)
__global__ void reduce_kernel(const unsigned short* __restrict__ part,
                              float* __restrict__ row_neg) {
    int r = blockIdx.x * 256 + threadIdx.x;
    const bf16x8* p = reinterpret_cast<const bf16x8*>(part + (size_t)r * NTILE);
    float s = 0.f;
#pragma unroll
    for (int k = 0; k < 4; k++) {
        bf16x8 a = p[k];
#pragma unroll
        for (int u = 0; u < 8; u++) s += bf2f((unsigned short)a[u]);
    }
    row_neg[r] = s;
}

// pair loss sum + fused finalize
__global__ void pair_kernel(const uint2* __restrict__ pairs,
                            const unsigned int* __restrict__ pair_cnt,
                            const float* __restrict__ row_neg,
                            unsigned int cap, double* __restrict__ loss,
                            unsigned int* __restrict__ done,
                            float* __restrict__ out) {
    __shared__ double red[256];
    unsigned int n = *pair_cnt;
    if (n > cap) n = cap;
    double local = 0.0;
    for (unsigned int p = blockIdx.x * blockDim.x + threadIdx.x; p < n;
         p += gridDim.x * blockDim.x) {
        uint2 e = pairs[p];
        int i = (int)(e.x >> 16), j = (int)(e.x & 0xffffu);
        float d = __int_as_float((int)e.y);
        float J = logf(row_neg[i] + row_neg[j]) + d;
        if (J > 0.f) local += (double)J * (double)J;
    }
    red[threadIdx.x] = local;
    __syncthreads();
    for (int s = 128; s; s >>= 1) {
        if (threadIdx.x < (unsigned)s) red[threadIdx.x] += red[threadIdx.x + s];
        __syncthreads();
    }
    if (threadIdx.x == 0) {
        atomicAdd(loss, red[0]);
        __threadfence();
        unsigned int tk = atomicAdd(done, 1u);
        if (tk == gridDim.x - 1) {
            double l = atomicAdd(loss, 0.0);
            out[0] = (float)(l / (2.0 * (double)(*pair_cnt)));
        }
    }
}

extern "C" void kernel_launch(void* const* d_in, const int* in_sizes, int n_in,
                              void* d_out, int out_size, void* d_ws, size_t ws_size,
                              hipStream_t stream) {
    const float* X = (const float*)d_in[0];
    const int* tgt = (const int*)d_in[1];
    float* out = (float*)d_out;

    char* ws = (char*)d_ws;
    double* loss            = (double*)(ws + CTRL_OFF);
    unsigned int* pair_cnt  = (unsigned int*)(ws + CTRL_OFF + 8);
    unsigned int* done      = (unsigned int*)(ws + CTRL_OFF + 12);
    unsigned int* absmax_u  = (unsigned int*)(ws + CTRL_OFF + 16);
    int* mag                = (int*)(ws + MAGI_OFF);
    float* row_neg          = (float*)(ws + RN_OFF);
    unsigned short* part    = (unsigned short*)(ws + PART_OFF);
    signed char* Xq         = (signed char*)(ws + XQ_OFF);
    uint2* pairs            = (uint2*)(ws + PAIR_OFF);
    unsigned int cap = 0;
    if (ws_size > PAIR_OFF + 8) cap = (unsigned int)((ws_size - PAIR_OFF) / 8);

    hipMemsetAsync(ws + CTRL_OFF, 0, 32, stream);   // loss/pair_cnt/done/absmax

    absmax_kernel<<<256, 256, 0, stream>>>(X, absmax_u);

    quant_kernel<<<NROWS / 4, 256, 0, stream>>>(X, Xq, mag, absmax_u);

    sim_mfma<<<NBLK, 256, 0, stream>>>(Xq, tgt, mag, absmax_u, part, pair_cnt,
                                       pairs, cap);

    reduce_kernel<<<NROWS / 256, 256, 0, stream>>>(part, row_neg);

    pair_kernel<<<256, 256, 0, stream>>>(pairs, pair_cnt, row_neg, cap, loss,
                                         done, out);
}

// Round 17
// 54.316 us; speedup vs baseline: 1.5770x; 1.2557x over previous
//
#include <hip/hip_runtime.h>
#include <math.h>

#define NROWS 4096
#define DIM   512
#define BM    128
#define BKB   128               // K-tile in elements(=bytes, int8)
#define NKT   (DIM / BKB)       // 4
#define NTILE (NROWS / BM)      // 32
#define NBLK  (NTILE * (NTILE + 1) / 2)  // 528 (= 8 x 66)

typedef __attribute__((ext_vector_type(4))) float f32x4;
typedef __attribute__((ext_vector_type(4))) int   i32x4;
typedef __attribute__((ext_vector_type(8))) short bf16x8;

// ws layout (bytes):
// [0, 32)            ctrl: double loss | uint pair_cnt | uint done | float inv_s
// [64, 1088)         float blockmax[256]
// [1088,  17472)     int   mag[4096]
// [17472, 33856)     float row_neg[4096]
// [33856, 296000)    ushort part_t[4096][32]  (bf16 negsum partials)
// [296000, 2393152)  int8 Xq[4096*512]  (2 MB)
// [2393152, ...)     pairs: uint2 {(i<<16)|j, float_bits(dist)}
#define CTRL_OFF 0
#define BMAX_OFF 64
#define MAGI_OFF 1088
#define RN_OFF   (MAGI_OFF + NROWS * 4)            // 17472
#define PART_OFF (RN_OFF + NROWS * 4)              // 33856
#define XQ_OFF   (PART_OFF + NROWS * NTILE * 2)    // 296000
#define PAIR_OFF (XQ_OFF + NROWS * DIM)            // 2393152

__device__ inline unsigned short f2bf(float f) {
    unsigned int u = __float_as_uint(f);
    unsigned int r = (u + 0x7fffu + ((u >> 16) & 1u)) >> 16;   // RTNE
    return (unsigned short)r;
}
__device__ inline float bf2f(unsigned short u) {
    return __uint_as_float((unsigned int)u << 16);
}

// pass 1: per-block abs-max (plain stores, no atomics, no pre-zero) + ctrl zero
__global__ void absmax_kernel(const float* __restrict__ X,
                              float* __restrict__ blockmax,
                              unsigned int* __restrict__ ctrl) {
    __shared__ float wm[4];
    if (blockIdx.x == 0 && threadIdx.x < 4) ctrl[threadIdx.x] = 0u;  // loss,pc,done
    float m = 0.f;
    for (int i = blockIdx.x * blockDim.x + threadIdx.x; i < NROWS * DIM / 4;
         i += gridDim.x * blockDim.x) {
        float4 v = reinterpret_cast<const float4*>(X)[i];
        m = fmaxf(m, fmaxf(fmaxf(fabsf(v.x), fabsf(v.y)),
                           fmaxf(fabsf(v.z), fabsf(v.w))));
    }
#pragma unroll
    for (int o = 32; o; o >>= 1) m = fmaxf(m, __shfl_down(m, o));
    if ((threadIdx.x & 63) == 0) wm[threadIdx.x >> 6] = m;
    __syncthreads();
    if (threadIdx.x == 0)
        blockmax[blockIdx.x] = fmaxf(fmaxf(wm[0], wm[1]), fmaxf(wm[2], wm[3]));
}

// parallel max of blockmax[256] (blockDim >= 256); uses tiny LDS scratch
__device__ inline float load_gmax(const float* __restrict__ blockmax,
                                  float* __restrict__ wm_s, float* __restrict__ gm_s) {
    int tid = threadIdx.x;
    float v = blockmax[tid & 255];
#pragma unroll
    for (int o = 32; o; o >>= 1) v = fmaxf(v, __shfl_down(v, o));
    if ((tid & 63) == 0 && tid < 256) wm_s[tid >> 6] = v;
    __syncthreads();
    if (tid == 0) *gm_s = fmaxf(fmaxf(wm_s[0], wm_s[1]), fmaxf(wm_s[2], wm_s[3]));
    __syncthreads();
    return *gm_s;
}

// pass 2: quantize to int8 + exact int row sq-norms; block 0 stores inv_s
__global__ void quant_kernel(const float* __restrict__ X,
                             signed char* __restrict__ Xq,
                             int* __restrict__ mag,
                             const float* __restrict__ blockmax,
                             float* __restrict__ inv_s_p) {
    __shared__ float wm[4], gm;
    float gmax = load_gmax(blockmax, wm, &gm);
    float s = gmax > 1e-20f ? 126.0f / gmax : 1.0f;
    if (blockIdx.x == 0 && threadIdx.x == 0)
        *inv_s_p = gmax > 1e-20f ? gmax * (1.0f / 126.0f) : 1.0f;

    int row  = blockIdx.x * 4 + (threadIdx.x >> 6);
    int lane = threadIdx.x & 63;
    const float4* p = reinterpret_cast<const float4*>(X + (size_t)row * DIM);
    unsigned int* o = reinterpret_cast<unsigned int*>(Xq + (size_t)row * DIM);
    int acc = 0;
#pragma unroll
    for (int q = lane; q < DIM / 4; q += 64) {
        float4 v = p[q];
        int c0 = (int)rintf(v.x * s), c1 = (int)rintf(v.y * s);
        int c2 = (int)rintf(v.z * s), c3 = (int)rintf(v.w * s);
        c0 = max(-127, min(127, c0)); c1 = max(-127, min(127, c1));
        c2 = max(-127, min(127, c2)); c3 = max(-127, min(127, c3));
        acc += c0 * c0 + c1 * c1 + c2 * c2 + c3 * c3;
        o[q] = (unsigned int)(c0 & 255) | ((unsigned int)(c1 & 255) << 8) |
               ((unsigned int)(c2 & 255) << 16) | ((unsigned int)(c3 & 255) << 24);
    }
#pragma unroll
    for (int off = 32; off; off >>= 1) acc += __shfl_down(acc, off);
    if (lane == 0) mag[row] = acc;
}

// int8 MFMA GEMM, exact integer distances. R11 structure: 128x128 triangular
// tiles, rolled K-loop, 8x16B-chunk XOR swizzle.
__global__ __launch_bounds__(256, 3) void sim_mfma(
        const signed char* __restrict__ Xq, const int* __restrict__ tgt,
        const int* __restrict__ mag, const float* __restrict__ inv_s_p,
        unsigned short* __restrict__ part,
        unsigned int* __restrict__ pair_cnt, uint2* __restrict__ pairs,
        unsigned int cap) {
    __shared__ signed char As[BM * BKB];   // 16 KB
    __shared__ signed char Bs[BM * BKB];   // 16 KB

    const int tid  = threadIdx.x;
    const int lane = tid & 63;
    const int wid  = tid >> 6;        // 4 waves: 2x2 of 64x64
    const int wr   = wid >> 1, wc = wid & 1;
    const int l15  = lane & 15;
    const int lg   = lane >> 4;       // 0..3

    const float inv_s = *inv_s_p;

    // XCD swizzle: 528 = 8 x 66, contiguous runs per XCD
    int b = blockIdx.x;
    int t = (b & 7) * 66 + (b >> 3);
    int bi = (int)((65.0f - sqrtf(4225.0f - 8.0f * (float)t)) * 0.5f);
    if (bi < 0) bi = 0;
    if (bi > NTILE - 1) bi = NTILE - 1;
    while ((65 * (bi + 1) - (bi + 1) * (bi + 1)) / 2 <= t) bi++;
    while ((65 * bi - bi * bi) / 2 > t) bi--;
    int bj = bi + (t - (65 * bi - bi * bi) / 2);
    const int rowBase = bi * BM;
    const int colBase = bj * BM;
    const bool offd = (bi != bj);

    i32x4 acc[4][4];
#pragma unroll
    for (int m = 0; m < 4; m++)
#pragma unroll
        for (int n = 0; n < 4; n++) acc[m][n] = (i32x4){0, 0, 0, 0};

    // ROLLED K-loop. Row = 128 B = 8 x 16B chunks; LDS slot (r, ch) holds
    // global chunk ch^(r&7) (read-side XOR, linear LDS dest - rule #21).
#pragma unroll 1
    for (int kt = 0; kt < NKT; kt++) {
        const int k0 = kt * BKB;
        __syncthreads();
#pragma unroll
        for (int c = 0; c < 4; c++) {
            int chunkBase = (c * 4 + wid) * 64;      // wave-uniform
            int idx = chunkBase + lane;              // 0..1023
            int r   = idx >> 3;
            int ch  = idx & 7;
            int gch = ch ^ (r & 7);
            const signed char* ga = Xq + (size_t)(rowBase + r) * DIM + k0 + gch * 16;
            __builtin_amdgcn_global_load_lds(
                (const __attribute__((address_space(1))) void*)ga,
                (__attribute__((address_space(3))) void*)(As + chunkBase * 16),
                16, 0, 0);
            const signed char* gb = Xq + (size_t)(colBase + r) * DIM + k0 + gch * 16;
            __builtin_amdgcn_global_load_lds(
                (const __attribute__((address_space(1))) void*)gb,
                (__attribute__((address_space(3))) void*)(Bs + chunkBase * 16),
                16, 0, 0);
        }
        __syncthreads();

#pragma unroll
        for (int ksub = 0; ksub < 2; ksub++) {
            i32x4 af[4], bf[4];
#pragma unroll
            for (int m = 0; m < 4; m++) {
                int ra = wr * 64 + m * 16 + l15;
                int cs = (ksub * 4 + lg) ^ (ra & 7);
                af[m] = *reinterpret_cast<const i32x4*>(&As[ra * BKB + cs * 16]);
            }
#pragma unroll
            for (int n = 0; n < 4; n++) {
                int rb = wc * 64 + n * 16 + l15;
                int cs = (ksub * 4 + lg) ^ (rb & 7);
                bf[n] = *reinterpret_cast<const i32x4*>(&Bs[rb * BKB + cs * 16]);
            }
#pragma unroll
            for (int m = 0; m < 4; m++)
#pragma unroll
                for (int n = 0; n < 4; n++)
                    acc[m][n] = __builtin_amdgcn_mfma_i32_16x16x64_i8(
                        af[m], bf[n], acc[m][n], 0, 0, 0);
        }
    }

    // ---- fused epilogue ----
    // C/D layout: col = lane&15, row = (lane>>4)*4 + reg (dtype-independent)
    int gcol[4], tgj[4], mj[4];
#pragma unroll
    for (int n = 0; n < 4; n++) {
        gcol[n] = colBase + wc * 64 + n * 16 + l15;
        tgj[n]  = tgt[gcol[n]];
        mj[n]   = mag[gcol[n]];
    }
    int grow[4][4], tgi[4][4], mi[4][4];
#pragma unroll
    for (int m = 0; m < 4; m++)
#pragma unroll
        for (int q = 0; q < 4; q++) {
            grow[m][q] = rowBase + wr * 64 + m * 16 + lg * 4 + q;
            tgi[m][q]  = tgt[grow[m][q]];
            mi[m][q]   = mag[grow[m][q]];
        }

    float negrow[4][4];
    float negcol[4] = {0.f, 0.f, 0.f, 0.f};
#pragma unroll
    for (int m = 0; m < 4; m++)
#pragma unroll
        for (int q = 0; q < 4; q++) negrow[m][q] = 0.f;

    // pass A: exact int d2 -> dist (overwrites acc with dist bits)
    int mycnt = 0;
#pragma unroll
    for (int m = 0; m < 4; m++)
#pragma unroll
        for (int n = 0; n < 4; n++)
#pragma unroll
            for (int q = 0; q < 4; q++) {
                int   d2   = mi[m][q] + mj[n] - 2 * acc[m][n][q];
                float dist = d2 > 0 ? sqrtf((float)d2) * inv_s : 0.f;
                acc[m][n][q] = __float_as_int(dist);
                if (tgi[m][q] != tgj[n]) {
                    if (d2 > 0) {
                        float e = __expf(1.0f - dist);
                        negrow[m][q] += e;
                        if (offd) negcol[n] += e;
                    }
                } else if (grow[m][q] < gcol[n]) {
                    mycnt++;
                }
            }

    __syncthreads();   // K-loop LDS dead; overlay epilogue buffers
    float* rowbuf = (float*)&As[0];            // [2][128] floats
    float* colbuf = (float*)&As[1024 * 2];     // [2][128] floats
    unsigned int* scan = (unsigned int*)&Bs[0];

#pragma unroll
    for (int m = 0; m < 4; m++)
#pragma unroll
        for (int q = 0; q < 4; q++) {
            float v = negrow[m][q];
            v += __shfl_xor(v, 1); v += __shfl_xor(v, 2);
            v += __shfl_xor(v, 4); v += __shfl_xor(v, 8);
            if (l15 == 0) rowbuf[wc * 128 + wr * 64 + m * 16 + lg * 4 + q] = v;
        }
#pragma unroll
    for (int n = 0; n < 4; n++) {
        float v = negcol[n];
        v += __shfl_xor(v, 16); v += __shfl_xor(v, 32);
        if (lg == 0) colbuf[wr * 128 + wc * 64 + n * 16 + l15] = v;
    }

    unsigned int pc = (unsigned int)mycnt;
    unsigned int incl = pc;
#pragma unroll
    for (int d = 1; d < 64; d <<= 1) {
        unsigned int tshf = __shfl_up(incl, d);
        if (lane >= d) incl += tshf;
    }
    if (lane == 63) scan[wid] = incl;
    __syncthreads();

    if (tid < BM) {
        float rv = rowbuf[tid] + rowbuf[128 + tid];
        part[(size_t)(rowBase + tid) * NTILE + bj] = f2bf(rv);
        if (offd) {
            float cv = colbuf[tid] + colbuf[128 + tid];
            part[(size_t)(colBase + tid) * NTILE + bi] = f2bf(cv);
        }
    }

    unsigned int woff = 0;
#pragma unroll
    for (int w = 0; w < 4; w++)
        if (w < wid) woff += scan[w];
    unsigned int btot = scan[0] + scan[1] + scan[2] + scan[3];
    if (tid == 0) scan[4] = btot ? atomicAdd(pair_cnt, btot) : 0u;
    __syncthreads();
    unsigned int mybase = scan[4] + woff + (incl - pc);

    if (pc) {
        unsigned int idx = mybase;
#pragma unroll
        for (int m = 0; m < 4; m++)
#pragma unroll
            for (int n = 0; n < 4; n++)
#pragma unroll
                for (int q = 0; q < 4; q++) {
                    if (tgi[m][q] == tgj[n] && grow[m][q] < gcol[n]) {
                        if (idx < cap) {
                            uint2 e;
                            e.x = ((unsigned int)grow[m][q] << 16) | (unsigned int)gcol[n];
                            e.y = (unsigned int)acc[m][n][q];   // dist bits
                            pairs[idx] = e;
                        }
                        idx++;
                    }
                }
    }
}

// row_neg[r] = sum of 32 bf16 partials (contiguous 64B stripe per row)
__global__ void reduce_kernel(const unsigned short* __restrict__ part,
                              float* __restrict__ row_neg) {
    int r = blockIdx.x * 256 + threadIdx.x;
    const bf16x8* p = reinterpret_cast<const bf16x8*>(part + (size_t)r * NTILE);
    float s = 0.f;
#pragma unroll
    for (int k = 0; k < 4; k++) {
        bf16x8 a = p[k];
#pragma unroll
        for (int u = 0; u < 8; u++) s += bf2f((unsigned short)a[u]);
    }
    row_neg[r] = s;
}

// pair loss sum + fused finalize
__global__ void pair_kernel(const uint2* __restrict__ pairs,
                            const unsigned int* __restrict__ pair_cnt,
                            const float* __restrict__ row_neg,
                            unsigned int cap, double* __restrict__ loss,
                            unsigned int* __restrict__ done,
                            float* __restrict__ out) {
    __shared__ double red[256];
    unsigned int n = *pair_cnt;
    if (n > cap) n = cap;
    double local = 0.0;
    for (unsigned int p = blockIdx.x * blockDim.x + threadIdx.x; p < n;
         p += gridDim.x * blockDim.x) {
        uint2 e = pairs[p];
        int i = (int)(e.x >> 16), j = (int)(e.x & 0xffffu);
        float d = __int_as_float((int)e.y);
        float J = logf(row_neg[i] + row_neg[j]) + d;
        if (J > 0.f) local += (double)J * (double)J;
    }
    red[threadIdx.x] = local;
    __syncthreads();
    for (int s = 128; s; s >>= 1) {
        if (threadIdx.x < (unsigned)s) red[threadIdx.x] += red[threadIdx.x + s];
        __syncthreads();
    }
    if (threadIdx.x == 0) {
        atomicAdd(loss, red[0]);
        __threadfence();
        unsigned int tk = atomicAdd(done, 1u);
        if (tk == gridDim.x - 1) {
            double l = atomicAdd(loss, 0.0);
            out[0] = (float)(l / (2.0 * (double)(*pair_cnt)));
        }
    }
}

extern "C" void kernel_launch(void* const* d_in, const int* in_sizes, int n_in,
                              void* d_out, int out_size, void* d_ws, size_t ws_size,
                              hipStream_t stream) {
    const float* X = (const float*)d_in[0];
    const int* tgt = (const int*)d_in[1];
    float* out = (float*)d_out;

    char* ws = (char*)d_ws;
    double* loss            = (double*)(ws + CTRL_OFF);
    unsigned int* pair_cnt  = (unsigned int*)(ws + CTRL_OFF + 8);
    unsigned int* done      = (unsigned int*)(ws + CTRL_OFF + 12);
    float* inv_s_p          = (float*)(ws + CTRL_OFF + 16);
    unsigned int* ctrl      = (unsigned int*)(ws + CTRL_OFF);
    float* blockmax         = (float*)(ws + BMAX_OFF);
    int* mag                = (int*)(ws + MAGI_OFF);
    float* row_neg          = (float*)(ws + RN_OFF);
    unsigned short* part    = (unsigned short*)(ws + PART_OFF);
    signed char* Xq         = (signed char*)(ws + XQ_OFF);
    uint2* pairs            = (uint2*)(ws + PAIR_OFF);
    unsigned int cap = 0;
    if (ws_size > PAIR_OFF + 8) cap = (unsigned int)((ws_size - PAIR_OFF) / 8);

    absmax_kernel<<<256, 256, 0, stream>>>(X, blockmax, ctrl);

    quant_kernel<<<NROWS / 4, 256, 0, stream>>>(X, Xq, mag, blockmax, inv_s_p);

    sim_mfma<<<NBLK, 256, 0, stream>>>(Xq, tgt, mag, inv_s_p, part, pair_cnt,
                                       pairs, cap);

    reduce_kernel<<<NROWS / 256, 256, 0, stream>>>(part, row_neg);

    pair_kernel<<<256, 256, 0, stream>>>(pairs, pair_cnt, row_neg, cap, loss,
                                         done, out);
}

// Round 19
// 48.801 us; speedup vs baseline: 1.7552x; 1.1130x over previous
//
#include <hip/hip_runtime.h>
#include <math.h>

#define NROWS 4096
#define DIM   512
#define BM    128
#define BKB   128               // K-tile in elements(=bytes, int8)
#define NKT   (DIM / BKB)       // 4
#define NTILE (NROWS / BM)      // 32
#define NBLK  (NTILE * (NTILE + 1) / 2)  // 528 (= 8 x 66)

typedef __attribute__((ext_vector_type(4))) float f32x4;
typedef __attribute__((ext_vector_type(4))) int   i32x4;
typedef __attribute__((ext_vector_type(8))) short bf16x8;

// ws layout (bytes):
// [0, 32)            ctrl: double loss | uint pair_cnt | uint done | pad
// [64,    16448)     float magf[4096]   (real-unit squared norms)
// [16448, 32832)     float srow[4096]   (per-row dequant scale)
// [32832, 49216)     float row_neg[4096]
// [49216, 311360)    ushort part_t[4096][32]  (bf16 negsum partials)
// [311360, 2408512)  int8 Xq[4096*512]  (2 MB)
// [2408512, ...)     pairs: uint2 {(i<<16)|j, float_bits(dist)}
#define CTRL_OFF 0
#define MAGF_OFF 64
#define SROW_OFF (MAGF_OFF + NROWS * 4)            // 16448
#define RN_OFF   (SROW_OFF + NROWS * 4)            // 32832
#define PART_OFF (RN_OFF + NROWS * 4)              // 49216
#define XQ_OFF   (PART_OFF + NROWS * NTILE * 2)    // 311360
#define PAIR_OFF (XQ_OFF + NROWS * DIM)            // 2408512

__device__ inline unsigned short f2bf(float f) {
    unsigned int u = __float_as_uint(f);
    unsigned int r = (u + 0x7fffu + ((u >> 16) & 1u)) >> 16;   // RTNE
    return (unsigned short)r;
}
__device__ inline float bf2f(unsigned short u) {
    return __uint_as_float((unsigned int)u << 16);
}

// quantize with PER-ROW scale (exact: d2 = |s_i q_i - s_j q_j|^2) + ctrl zero.
// One wave per row; row (2 KB) held in registers, single pass over X.
__global__ void quant_kernel(const float* __restrict__ X,
                             signed char* __restrict__ Xq,
                             float* __restrict__ magf,
                             float* __restrict__ srow,
                             unsigned int* __restrict__ ctrl) {
    if (blockIdx.x == 0 && threadIdx.x < 4) ctrl[threadIdx.x] = 0u;
    int row  = blockIdx.x * 4 + (threadIdx.x >> 6);
    int lane = threadIdx.x & 63;
    const float4* p = reinterpret_cast<const float4*>(X + (size_t)row * DIM);
    float4 v0 = p[lane], v1 = p[lane + 64];
    float m = fmaxf(fmaxf(fmaxf(fabsf(v0.x), fabsf(v0.y)),
                          fmaxf(fabsf(v0.z), fabsf(v0.w))),
                    fmaxf(fmaxf(fabsf(v1.x), fabsf(v1.y)),
                          fmaxf(fabsf(v1.z), fabsf(v1.w))));
#pragma unroll
    for (int o = 1; o < 64; o <<= 1) m = fmaxf(m, __shfl_xor(m, o));
    float s = m > 1e-20f ? 126.0f / m : 1.0f;

    int c[8];
    c[0] = (int)rintf(v0.x * s); c[1] = (int)rintf(v0.y * s);
    c[2] = (int)rintf(v0.z * s); c[3] = (int)rintf(v0.w * s);
    c[4] = (int)rintf(v1.x * s); c[5] = (int)rintf(v1.y * s);
    c[6] = (int)rintf(v1.z * s); c[7] = (int)rintf(v1.w * s);
    int acc = 0;
#pragma unroll
    for (int k = 0; k < 8; k++) {
        c[k] = max(-127, min(127, c[k]));
        acc += c[k] * c[k];
    }
    unsigned int* o = reinterpret_cast<unsigned int*>(Xq + (size_t)row * DIM);
    o[lane] = (unsigned int)(c[0] & 255) | ((unsigned int)(c[1] & 255) << 8) |
              ((unsigned int)(c[2] & 255) << 16) | ((unsigned int)(c[3] & 255) << 24);
    o[lane + 64] = (unsigned int)(c[4] & 255) | ((unsigned int)(c[5] & 255) << 8) |
                   ((unsigned int)(c[6] & 255) << 16) | ((unsigned int)(c[7] & 255) << 24);
#pragma unroll
    for (int off = 32; off; off >>= 1) acc += __shfl_down(acc, off);
    if (lane == 0) {
        float sr = 1.0f / s;                    // dequant scale
        srow[row] = sr;
        magf[row] = (sr * sr) * (float)acc;     // real-unit |x_q|^2
    }
}

// int8 MFMA GEMM, exact quantized distances. R17's proven structure:
// 128x128 triangular tiles, rolled NKT=4 K-loop, 8x16B-chunk XOR swizzle.
__global__ __launch_bounds__(256, 3) void sim_mfma(
        const signed char* __restrict__ Xq, const int* __restrict__ tgt,
        const float* __restrict__ magf, const float* __restrict__ srow,
        unsigned short* __restrict__ part,
        unsigned int* __restrict__ pair_cnt, uint2* __restrict__ pairs,
        unsigned int cap) {
    __shared__ signed char As[BM * BKB];   // 16 KB
    __shared__ signed char Bs[BM * BKB];   // 16 KB

    const int tid  = threadIdx.x;
    const int lane = tid & 63;
    const int wid  = tid >> 6;        // 4 waves: 2x2 of 64x64
    const int wr   = wid >> 1, wc = wid & 1;
    const int l15  = lane & 15;
    const int lg   = lane >> 4;       // 0..3

    // XCD swizzle: 528 = 8 x 66, contiguous runs per XCD
    int b = blockIdx.x;
    int t = (b & 7) * 66 + (b >> 3);
    int bi = (int)((65.0f - sqrtf(4225.0f - 8.0f * (float)t)) * 0.5f);
    if (bi < 0) bi = 0;
    if (bi > NTILE - 1) bi = NTILE - 1;
    while ((65 * (bi + 1) - (bi + 1) * (bi + 1)) / 2 <= t) bi++;
    while ((65 * bi - bi * bi) / 2 > t) bi--;
    int bj = bi + (t - (65 * bi - bi * bi) / 2);
    const int rowBase = bi * BM;
    const int colBase = bj * BM;
    const bool offd = (bi != bj);

    i32x4 acc[4][4];
#pragma unroll
    for (int m = 0; m < 4; m++)
#pragma unroll
        for (int n = 0; n < 4; n++) acc[m][n] = (i32x4){0, 0, 0, 0};

    // ROLLED K-loop. Row = 128 B = 8 x 16B chunks; LDS slot (r, ch) holds
    // global chunk ch^(r&7) (read-side XOR, linear LDS dest - rule #21).
#pragma unroll 1
    for (int kt = 0; kt < NKT; kt++) {
        const int k0 = kt * BKB;
        __syncthreads();
#pragma unroll
        for (int c = 0; c < 4; c++) {
            int chunkBase = (c * 4 + wid) * 64;      // wave-uniform
            int idx = chunkBase + lane;              // 0..1023
            int r   = idx >> 3;
            int ch  = idx & 7;
            int gch = ch ^ (r & 7);
            const signed char* ga = Xq + (size_t)(rowBase + r) * DIM + k0 + gch * 16;
            __builtin_amdgcn_global_load_lds(
                (const __attribute__((address_space(1))) void*)ga,
                (__attribute__((address_space(3))) void*)(As + chunkBase * 16),
                16, 0, 0);
            const signed char* gb = Xq + (size_t)(colBase + r) * DIM + k0 + gch * 16;
            __builtin_amdgcn_global_load_lds(
                (const __attribute__((address_space(1))) void*)gb,
                (__attribute__((address_space(3))) void*)(Bs + chunkBase * 16),
                16, 0, 0);
        }
        __syncthreads();

#pragma unroll
        for (int ksub = 0; ksub < 2; ksub++) {
            i32x4 af[4], bf[4];
#pragma unroll
            for (int m = 0; m < 4; m++) {
                int ra = wr * 64 + m * 16 + l15;
                int cs = (ksub * 4 + lg) ^ (ra & 7);
                af[m] = *reinterpret_cast<const i32x4*>(&As[ra * BKB + cs * 16]);
            }
#pragma unroll
            for (int n = 0; n < 4; n++) {
                int rb = wc * 64 + n * 16 + l15;
                int cs = (ksub * 4 + lg) ^ (rb & 7);
                bf[n] = *reinterpret_cast<const i32x4*>(&Bs[rb * BKB + cs * 16]);
            }
#pragma unroll
            for (int m = 0; m < 4; m++)
#pragma unroll
                for (int n = 0; n < 4; n++)
                    acc[m][n] = __builtin_amdgcn_mfma_i32_16x16x64_i8(
                        af[m], bf[n], acc[m][n], 0, 0, 0);
        }
    }

    // ---- fused epilogue ----
    // C/D layout: col = lane&15, row = (lane>>4)*4 + reg (dtype-independent)
    int gcol[4], tgj[4];
    float mj[4], sj[4];
#pragma unroll
    for (int n = 0; n < 4; n++) {
        gcol[n] = colBase + wc * 64 + n * 16 + l15;
        tgj[n]  = tgt[gcol[n]];
        mj[n]   = magf[gcol[n]];
        sj[n]   = srow[gcol[n]];
    }
    int grow[4][4], tgi[4][4];
    float mi[4][4], si[4][4];
#pragma unroll
    for (int m = 0; m < 4; m++)
#pragma unroll
        for (int q = 0; q < 4; q++) {
            grow[m][q] = rowBase + wr * 64 + m * 16 + lg * 4 + q;
            tgi[m][q]  = tgt[grow[m][q]];
            mi[m][q]   = magf[grow[m][q]];
            si[m][q]   = srow[grow[m][q]];
        }

    float negrow[4][4];
    float negcol[4] = {0.f, 0.f, 0.f, 0.f};
#pragma unroll
    for (int m = 0; m < 4; m++)
#pragma unroll
        for (int q = 0; q < 4; q++) negrow[m][q] = 0.f;

    // pass A: real-unit d2 -> dist (overwrites acc with dist bits)
    int mycnt = 0;
#pragma unroll
    for (int m = 0; m < 4; m++)
#pragma unroll
        for (int n = 0; n < 4; n++)
#pragma unroll
            for (int q = 0; q < 4; q++) {
                float ss   = si[m][q] * sj[n];
                float d2   = (mi[m][q] + mj[n]) - 2.0f * (ss * (float)acc[m][n][q]);
                float dist = d2 > 0.f ? sqrtf(d2) : 0.f;
                acc[m][n][q] = __float_as_int(dist);
                if (tgi[m][q] != tgj[n]) {
                    if (dist != 0.f) {
                        float e = __expf(1.0f - dist);
                        negrow[m][q] += e;
                        if (offd) negcol[n] += e;
                    }
                } else if (grow[m][q] < gcol[n]) {
                    mycnt++;
                }
            }

    __syncthreads();   // K-loop LDS dead; overlay epilogue buffers
    float* rowbuf = (float*)&As[0];            // [2][128] floats
    float* colbuf = (float*)&As[2048];         // [2][128] floats
    unsigned int* scan = (unsigned int*)&Bs[0];

#pragma unroll
    for (int m = 0; m < 4; m++)
#pragma unroll
        for (int q = 0; q < 4; q++) {
            float v = negrow[m][q];
            v += __shfl_xor(v, 1); v += __shfl_xor(v, 2);
            v += __shfl_xor(v, 4); v += __shfl_xor(v, 8);
            if (l15 == 0) rowbuf[wc * 128 + wr * 64 + m * 16 + lg * 4 + q] = v;
        }
#pragma unroll
    for (int n = 0; n < 4; n++) {
        float v = negcol[n];
        v += __shfl_xor(v, 16); v += __shfl_xor(v, 32);
        if (lg == 0) colbuf[wr * 128 + wc * 64 + n * 16 + l15] = v;
    }

    unsigned int pc = (unsigned int)mycnt;
    unsigned int incl = pc;
#pragma unroll
    for (int d = 1; d < 64; d <<= 1) {
        unsigned int tshf = __shfl_up(incl, d);
        if (lane >= d) incl += tshf;
    }
    if (lane == 63) scan[wid] = incl;
    __syncthreads();

    if (tid < BM) {
        float rv = rowbuf[tid] + rowbuf[128 + tid];
        part[(size_t)(rowBase + tid) * NTILE + bj] = f2bf(rv);
        if (offd) {
            float cv = colbuf[tid] + colbuf[128 + tid];
            part[(size_t)(colBase + tid) * NTILE + bi] = f2bf(cv);
        }
    }

    unsigned int woff = 0;
#pragma unroll
    for (int w = 0; w < 4; w++)
        if (w < wid) woff += scan[w];
    unsigned int btot = scan[0] + scan[1] + scan[2] + scan[3];
    if (tid == 0) scan[4] = btot ? atomicAdd(pair_cnt, btot) : 0u;
    __syncthreads();
    unsigned int mybase = scan[4] + woff + (incl - pc);

    if (pc) {
        unsigned int idx = mybase;
#pragma unroll
        for (int m = 0; m < 4; m++)
#pragma unroll
            for (int n = 0; n < 4; n++)
#pragma unroll
                for (int q = 0; q < 4; q++) {
                    if (tgi[m][q] == tgj[n] && grow[m][q] < gcol[n]) {
                        if (idx < cap) {
                            uint2 e;
                            e.x = ((unsigned int)grow[m][q] << 16) | (unsigned int)gcol[n];
                            e.y = (unsigned int)acc[m][n][q];   // dist bits
                            pairs[idx] = e;
                        }
                        idx++;
                    }
                }
    }
}

// row_neg[r] = sum of 32 bf16 partials (contiguous 64B stripe per row)
__global__ void reduce_kernel(const unsigned short* __restrict__ part,
                              float* __restrict__ row_neg) {
    int r = blockIdx.x * 256 + threadIdx.x;
    const bf16x8* p = reinterpret_cast<const bf16x8*>(part + (size_t)r * NTILE);
    float s = 0.f;
#pragma unroll
    for (int k = 0; k < 4; k++) {
        bf16x8 a = p[k];
#pragma unroll
        for (int u = 0; u < 8; u++) s += bf2f((unsigned short)a[u]);
    }
    row_neg[r] = s;
}

// pair loss sum + fused finalize
__global__ void pair_kernel(const uint2* __restrict__ pairs,
                            const unsigned int* __restrict__ pair_cnt,
                            const float* __restrict__ row_neg,
                            unsigned int cap, double* __restrict__ loss,
                            unsigned int* __restrict__ done,
                            float* __restrict__ out) {
    __shared__ double red[256];
    unsigned int n = *pair_cnt;
    if (n > cap) n = cap;
    double local = 0.0;
    for (unsigned int p = blockIdx.x * blockDim.x + threadIdx.x; p < n;
         p += gridDim.x * blockDim.x) {
        uint2 e = pairs[p];
        int i = (int)(e.x >> 16), j = (int)(e.x & 0xffffu);
        float d = __int_as_float((int)e.y);
        float J = logf(row_neg[i] + row_neg[j]) + d;
        if (J > 0.f) local += (double)J * (double)J;
    }
    red[threadIdx.x] = local;
    __syncthreads();
    for (int s = 128; s; s >>= 1) {
        if (threadIdx.x < (unsigned)s) red[threadIdx.x] += red[threadIdx.x + s];
        __syncthreads();
    }
    if (threadIdx.x == 0) {
        atomicAdd(loss, red[0]);
        __threadfence();
        unsigned int tk = atomicAdd(done, 1u);
        if (tk == gridDim.x - 1) {
            double l = atomicAdd(loss, 0.0);
            out[0] = (float)(l / (2.0 * (double)(*pair_cnt)));
        }
    }
}

extern "C" void kernel_launch(void* const* d_in, const int* in_sizes, int n_in,
                              void* d_out, int out_size, void* d_ws, size_t ws_size,
                              hipStream_t stream) {
    const float* X = (const float*)d_in[0];
    const int* tgt = (const int*)d_in[1];
    float* out = (float*)d_out;

    char* ws = (char*)d_ws;
    double* loss            = (double*)(ws + CTRL_OFF);
    unsigned int* pair_cnt  = (unsigned int*)(ws + CTRL_OFF + 8);
    unsigned int* done      = (unsigned int*)(ws + CTRL_OFF + 12);
    unsigned int* ctrl      = (unsigned int*)(ws + CTRL_OFF);
    float* magf             = (float*)(ws + MAGF_OFF);
    float* srow             = (float*)(ws + SROW_OFF);
    float* row_neg          = (float*)(ws + RN_OFF);
    unsigned short* part    = (unsigned short*)(ws + PART_OFF);
    signed char* Xq         = (signed char*)(ws + XQ_OFF);
    uint2* pairs            = (uint2*)(ws + PAIR_OFF);
    unsigned int cap = 0;
    if (ws_size > PAIR_OFF + 8) cap = (unsigned int)((ws_size - PAIR_OFF) / 8);

    quant_kernel<<<NROWS / 4, 256, 0, stream>>>(X, Xq, magf, srow, ctrl);

    sim_mfma<<<NBLK, 256, 0, stream>>>(Xq, tgt, magf, srow, part, pair_cnt,
                                       pairs, cap);

    reduce_kernel<<<NROWS / 256, 256, 0, stream>>>(part, row_neg);

    pair_kernel<<<256, 256, 0, stream>>>(pairs, pair_cnt, row_neg, cap, loss,
                                         done, out);
}